// Round 4
// baseline (232.647 us; speedup 1.0000x reference)
//
#include <hip/hip_runtime.h>
#include <hip/hip_cooperative_groups.h>
#include <hip/hip_bf16.h>
#include <math.h>

namespace cg = cooperative_groups;

// Problem constants
#define C_CH   256
#define H_DIM  26
#define W_DIM  26
#define HW     (H_DIM * W_DIM)        // 676
#define N_BOX  128
#define OUTP   3
#define NBIN   (OUTP * OUTP)          // 9
#define FEAT   (C_CH * NBIN)          // 2304
#define H1     1024
#define H2     512

#define A_GEMV_TASKS (H1 / 4)                 // 256 (4 rows per task-block)
#define A_TASKS      (A_GEMV_TASKS + HW)      // 932
#define B_GEMV_TASKS (FEAT / 4)               // 576
#define B_ROI_TASKS  (N_BOX * NBIN)           // 1152
#define B_TASKS      (B_GEMV_TASKS + B_ROI_TASKS + 1)  // 1729

#define GRID_BLOCKS  1024                     // 4 blocks/CU co-resident

// ---------------------------------------------------------------------------
// Wave-per-row GEMV with float4 loads: dot(M[r,:], v). K % 256 == 0.
// ---------------------------------------------------------------------------
__device__ __forceinline__ float gemv_row_f4(const float* __restrict__ M,
                                             const float* __restrict__ v,
                                             int r, int K, int lane) {
    const float4* row = (const float4*)(M + (size_t)r * K);
    const float4* vv  = (const float4*)v;
    float s = 0.f;
    for (int k4 = lane; k4 < (K >> 2); k4 += 64) {
        float4 a = row[k4], b = vv[k4];
        s += a.x * b.x + a.y * b.y + a.z * b.z + a.w * b.w;
    }
    #pragma unroll
    for (int off = 32; off; off >>= 1) s += __shfl_down(s, off, 64);
    return s;
}

// ---------------------------------------------------------------------------
// Single cooperative kernel: 3 stages separated by grid.sync().
// ---------------------------------------------------------------------------
__global__ __launch_bounds__(256, 4)
void fused_all(const float* __restrict__ W2, const float* __restrict__ w3,
               float* __restrict__ v,
               const float* __restrict__ x, float* __restrict__ xT,
               const float* __restrict__ W1, float* __restrict__ wvec2,
               const int* __restrict__ det, float* __restrict__ feats,
               const float* __restrict__ b1, const float* __restrict__ b2,
               const float* __restrict__ b3, float* __restrict__ cb,
               float* __restrict__ out) {
    cg::grid_group grid = cg::this_grid();
    const int nb   = gridDim.x;
    const int tid  = threadIdx.x;
    const int lane = tid & 63;
    const int wid  = tid >> 6;
    __shared__ float red[4];

    // ---------------- Stage A: v = W2@W3  ||  transpose x -> xT ----------------
    for (int t = blockIdx.x; t < A_TASKS; t += nb) {
        if (t < A_GEMV_TASKS) {
            int r = t * 4 + wid;
            float s = gemv_row_f4(W2, w3, r, H2, lane);
            if (lane == 0) v[r] = s;
        } else {
            int p = t - A_GEMV_TASKS;            // pixel 0..675
            xT[p * C_CH + tid] = x[(size_t)tid * HW + p];
        }
    }
    grid.sync();

    // ---------------- Stage B: wvec2 = W1@v (bin-major) || ROI max || bias ------
    for (int t = blockIdx.x; t < B_TASKS; t += nb) {
        if (t < B_GEMV_TASKS) {
            int r = t * 4 + wid;                 // r = c*9 + bin
            float s = gemv_row_f4(W1, v, r, H1, lane);
            if (lane == 0) wvec2[(r % NBIN) * C_CH + (r / NBIN)] = s;
        } else if (t < B_GEMV_TASKS + B_ROI_TASKS) {
            int nbx = t - B_GEMV_TASKS;
            int n = nbx / NBIN, bin = nbx - n * NBIN;
            int bi = bin / OUTP, bj = bin - bi * OUTP;

            int x1 = det[n * 4 + 0], y1 = det[n * 4 + 1];
            int x2 = det[n * 4 + 2], y2 = det[n * 4 + 3];
            int hl = y2 - y1 + 1, wl = x2 - x1 + 1;

            int h0  = y1 + (bi * hl) / OUTP;
            int h1e = y1 + ((bi + 1) * hl + OUTP - 1) / OUTP;
            int w0  = x1 + (bj * wl) / OUTP;
            int w1e = x1 + ((bj + 1) * wl + OUTP - 1) / OUTP;

            float m = -INFINITY;
            for (int h = h0; h < h1e; h++) {
                const float* rowp = xT + (size_t)(h * W_DIM) * C_CH + tid;
                for (int w = w0; w < w1e; w++)
                    m = fmaxf(m, rowp[(size_t)w * C_CH]);
            }
            feats[(size_t)n * FEAT + bin * C_CH + tid] = m;   // coalesced
        } else {
            // collapsed bias: cb = b1.v + b2.w3 + b3
            float s = 0.f;
            for (int k = tid; k < H1; k += 256) s += b1[k] * v[k];
            for (int k = tid; k < H2; k += 256) s += b2[k] * w3[k];
            #pragma unroll
            for (int off = 32; off; off >>= 1) s += __shfl_down(s, off, 64);
            if (lane == 0) red[wid] = s;
            __syncthreads();
            if (tid == 0) cb[0] = red[0] + red[1] + red[2] + red[3] + b3[0];
            __syncthreads();
        }
    }
    grid.sync();

    // ---------------- Stage C: out[n] = softplus(dot(feats[n], wvec2) + cb) -----
    for (int t = blockIdx.x; t < N_BOX; t += nb) {
        const float* f = feats + (size_t)t * FEAT;
        float s = 0.f;
        #pragma unroll
        for (int j = 0; j < NBIN; j++) s += f[j * C_CH + tid] * wvec2[j * C_CH + tid];
        #pragma unroll
        for (int off = 32; off; off >>= 1) s += __shfl_down(s, off, 64);
        if (lane == 0) red[wid] = s;
        __syncthreads();
        if (tid == 0) {
            float r = red[0] + red[1] + red[2] + red[3] + cb[0];
            out[t] = fmaxf(r, 0.f) + log1pf(expf(-fabsf(r)));  // stable softplus
        }
        __syncthreads();
    }
}

extern "C" void kernel_launch(void* const* d_in, const int* in_sizes, int n_in,
                              void* d_out, int out_size, void* d_ws, size_t ws_size,
                              hipStream_t stream) {
    const float* x   = (const float*)d_in[0];
    const int*   det = (const int*)  d_in[1];
    const float* W1  = (const float*)d_in[2];
    const float* b1  = (const float*)d_in[3];
    const float* W2  = (const float*)d_in[4];
    const float* b2  = (const float*)d_in[5];
    const float* W3  = (const float*)d_in[6];
    const float* b3  = (const float*)d_in[7];
    float* out = (float*)d_out;

    float* ws    = (float*)d_ws;
    float* xT    = ws;                              // 173056 floats
    float* v     = xT + (size_t)HW * C_CH;          // 1024
    float* wvec2 = v + H1;                          // 2304 (bin-major)
    float* feats = wvec2 + FEAT;                    // 294912
    float* cb    = feats + (size_t)N_BOX * FEAT;    // 1

    void* args[] = {
        (void*)&W2, (void*)&W3, (void*)&v, (void*)&x, (void*)&xT,
        (void*)&W1, (void*)&wvec2, (void*)&det, (void*)&feats,
        (void*)&b1, (void*)&b2, (void*)&b3, (void*)&cb, (void*)&out
    };
    hipLaunchCooperativeKernel((void*)fused_all, dim3(GRID_BLOCKS), dim3(256),
                               args, 0, stream);
}

// Round 5
// 17.185 us; speedup vs baseline: 13.5380x; 13.5380x over previous
//
#include <hip/hip_runtime.h>
#include <hip/hip_bf16.h>
#include <math.h>

// Problem constants
#define C_CH   256
#define H_DIM  26
#define W_DIM  26
#define HW     (H_DIM * W_DIM)      // 676
#define N_BOX  128
#define OUTP   3
#define NBIN   (OUTP * OUTP)        // 9
#define FEAT   (C_CH * NBIN)        // 2304
#define H1     1024
#define H2     512

#define KA_GEMV_BLOCKS (H1 / 4)       // 256
#define KB_GEMV_BLOCKS (FEAT / 4)     // 576
#define KB_ROI_BLOCKS  (N_BOX * NBIN) // 1152

#define NEGINF (-1.0f/0.0f)

// ---------------------------------------------------------------------------
// Wave-per-row GEMV with float4 loads: dot(M[r,:], v). K % 256 == 0.
// ---------------------------------------------------------------------------
__device__ __forceinline__ float gemv_row_f4(const float* __restrict__ M,
                                             const float* __restrict__ v,
                                             int r, int K, int lane) {
    const float4* row = (const float4*)(M + (size_t)r * K);
    const float4* vv  = (const float4*)v;
    float s = 0.f;
    for (int k4 = lane; k4 < (K >> 2); k4 += 64) {
        float4 a = row[k4], b = vv[k4];
        s += a.x * b.x + a.y * b.y + a.z * b.z + a.w * b.w;
    }
    #pragma unroll
    for (int off = 32; off; off >>= 1) s += __shfl_down(s, off, 64);
    return s;
}

// ---------------------------------------------------------------------------
// K_A: v = W2 @ W3 (blocks 0..255) || transpose x -> xT [pixel][channel]
// ---------------------------------------------------------------------------
__global__ void kA(const float* __restrict__ W2, const float* __restrict__ w3,
                   float* __restrict__ v,
                   const float* __restrict__ x, float* __restrict__ xT) {
    if (blockIdx.x < KA_GEMV_BLOCKS) {
        int r = blockIdx.x * 4 + (threadIdx.x >> 6);
        int lane = threadIdx.x & 63;
        float s = gemv_row_f4(W2, w3, r, H2, lane);
        if (lane == 0) v[r] = s;
    } else {
        int p = blockIdx.x - KA_GEMV_BLOCKS;    // pixel 0..675
        xT[p * C_CH + threadIdx.x] = x[(size_t)threadIdx.x * HW + p];
    }
}

// ---------------------------------------------------------------------------
// K_B: wvec2[bin*256+c] = dot(W1[c*9+bin,:], v)   (blocks 0..575)
//   || feats[n][bin*256+c] = ROI-bin max          (blocks 576..1727)
//        - pixel offsets precomputed to LDS, 8 independent load chains (ILP)
//   || cb = b1.v + b2.w3 + b3                     (block 1728)
// ---------------------------------------------------------------------------
__global__ void kB(const float* __restrict__ W1, const float* __restrict__ v,
                   float* __restrict__ wvec2,
                   const float* __restrict__ xT, const int* __restrict__ det,
                   float* __restrict__ feats,
                   const float* __restrict__ b1, const float* __restrict__ b2,
                   const float* __restrict__ w3, const float* __restrict__ b3,
                   float* __restrict__ cb) {
    __shared__ int offs[81];
    __shared__ float red[4];
    int b = blockIdx.x;
    int tid = threadIdx.x;

    if (b < KB_GEMV_BLOCKS) {
        int r = b * 4 + (tid >> 6);              // r = c*9 + bin
        int lane = tid & 63;
        float s = gemv_row_f4(W1, v, r, H1, lane);
        if (lane == 0) wvec2[(r % NBIN) * C_CH + (r / NBIN)] = s;
    } else if (b < KB_GEMV_BLOCKS + KB_ROI_BLOCKS) {
        int nbx = b - KB_GEMV_BLOCKS;
        int n = nbx / NBIN, bin = nbx - n * NBIN;
        int bi = bin / OUTP, bj = bin - bi * OUTP;

        int x1 = det[n * 4 + 0], y1 = det[n * 4 + 1];
        int x2 = det[n * 4 + 2], y2 = det[n * 4 + 3];
        int hl = y2 - y1 + 1, wl = x2 - x1 + 1;

        int h0  = y1 + (bi * hl) / OUTP;
        int h1e = y1 + ((bi + 1) * hl + OUTP - 1) / OUTP;
        int w0  = x1 + (bj * wl) / OUTP;
        int w1e = x1 + ((bj + 1) * wl + OUTP - 1) / OUTP;
        int hb = h1e - h0, wb = w1e - w0;
        int cnt = hb * wb;                        // 1..81, uniform per block

        if (tid < cnt) {                          // parallel offset precompute
            int ph = tid / wb, pw = tid - ph * wb;
            offs[tid] = ((h0 + ph) * W_DIM + (w0 + pw)) * C_CH;
        }
        __syncthreads();

        const float* xc = xT + tid;               // channel = tid
        float m0 = NEGINF, m1 = NEGINF, m2 = NEGINF, m3 = NEGINF;
        float m4 = NEGINF, m5 = NEGINF, m6 = NEGINF, m7 = NEGINF;
        int p = 0;
        for (; p + 8 <= cnt; p += 8) {            // 8 independent load chains
            float v0 = xc[offs[p + 0]], v1 = xc[offs[p + 1]];
            float v2 = xc[offs[p + 2]], v3 = xc[offs[p + 3]];
            float v4 = xc[offs[p + 4]], v5 = xc[offs[p + 5]];
            float v6 = xc[offs[p + 6]], v7 = xc[offs[p + 7]];
            m0 = fmaxf(m0, v0); m1 = fmaxf(m1, v1);
            m2 = fmaxf(m2, v2); m3 = fmaxf(m3, v3);
            m4 = fmaxf(m4, v4); m5 = fmaxf(m5, v5);
            m6 = fmaxf(m6, v6); m7 = fmaxf(m7, v7);
        }
        for (; p < cnt; p++) m0 = fmaxf(m0, xc[offs[p]]);
        float m = fmaxf(fmaxf(fmaxf(m0, m1), fmaxf(m2, m3)),
                        fmaxf(fmaxf(m4, m5), fmaxf(m6, m7)));
        feats[(size_t)n * FEAT + bin * C_CH + tid] = m;   // coalesced 1KB store
    } else {
        // collapsed bias: cb = b1.v + b2.w3 + b3
        float s = 0.f;
        for (int k = tid; k < H1; k += 256) s += b1[k] * v[k];
        for (int k = tid; k < H2; k += 256) s += b2[k] * w3[k];
        #pragma unroll
        for (int off = 32; off; off >>= 1) s += __shfl_down(s, off, 64);
        int lane = tid & 63, wid = tid >> 6;
        if (lane == 0) red[wid] = s;
        __syncthreads();
        if (tid == 0) cb[0] = red[0] + red[1] + red[2] + red[3] + b3[0];
    }
}

// ---------------------------------------------------------------------------
// K_C: out[n] = softplus(dot(feats[n], wvec2) + cb)
// ---------------------------------------------------------------------------
__global__ void kC(const float* __restrict__ feats, const float* __restrict__ wvec2,
                   const float* __restrict__ cb, float* __restrict__ out) {
    int n = blockIdx.x, t = threadIdx.x;
    const float* f = feats + (size_t)n * FEAT;
    float s = 0.f;
    #pragma unroll
    for (int j = 0; j < NBIN; j++) s += f[j * C_CH + t] * wvec2[j * C_CH + t];
    #pragma unroll
    for (int off = 32; off; off >>= 1) s += __shfl_down(s, off, 64);
    __shared__ float red[4];
    int lane = t & 63, wid = t >> 6;
    if (lane == 0) red[wid] = s;
    __syncthreads();
    if (t == 0) {
        float r = red[0] + red[1] + red[2] + red[3] + cb[0];
        out[n] = fmaxf(r, 0.f) + log1pf(expf(-fabsf(r)));   // stable softplus
    }
}

extern "C" void kernel_launch(void* const* d_in, const int* in_sizes, int n_in,
                              void* d_out, int out_size, void* d_ws, size_t ws_size,
                              hipStream_t stream) {
    const float* x   = (const float*)d_in[0];
    const int*   det = (const int*)  d_in[1];
    const float* W1  = (const float*)d_in[2];
    const float* b1  = (const float*)d_in[3];
    const float* W2  = (const float*)d_in[4];
    const float* b2  = (const float*)d_in[5];
    const float* W3  = (const float*)d_in[6];
    const float* b3  = (const float*)d_in[7];
    float* out = (float*)d_out;

    float* ws    = (float*)d_ws;
    float* xT    = ws;                              // 173056 floats
    float* v     = xT + (size_t)HW * C_CH;          // 1024
    float* wvec2 = v + H1;                          // 2304 (bin-major)
    float* feats = wvec2 + FEAT;                    // 294912
    float* cb    = feats + (size_t)N_BOX * FEAT;    // 1

    kA<<<KA_GEMV_BLOCKS + HW, 256, 0, stream>>>(W2, W3, v, x, xT);
    kB<<<KB_GEMV_BLOCKS + KB_ROI_BLOCKS + 1, 256, 0, stream>>>(
        W1, v, wvec2, xT, det, feats, b1, b2, W3, b3, cb);
    kC<<<N_BOX, 256, 0, stream>>>(feats, wvec2, cb, out);
}